// Round 4
// baseline (511.820 us; speedup 1.0000x reference)
//
#include <hip/hip_runtime.h>

#define AS1 __attribute__((address_space(1)))
#define AS3 __attribute__((address_space(3)))

typedef __attribute__((ext_vector_type(8))) __bf16 bf16x8;
typedef __attribute__((ext_vector_type(8))) unsigned short ushort8;
typedef __attribute__((ext_vector_type(4))) float f32x4;

static constexpr int N  = 8192;
static constexpr int P  = 128;
static constexpr int D  = 256;
static constexpr int KC = 384;   // P + D concatenated K

__device__ __forceinline__ unsigned short f32_bf16(float f) {
  union { float f; unsigned u; } v; v.f = f;
  unsigned r = v.u + 0x7fffu + ((v.u >> 16) & 1u);   // round-to-nearest-even
  return (unsigned short)(r >> 16);
}

__device__ __forceinline__ void glds16(const void* g, void* l) {
  __builtin_amdgcn_global_load_lds((const AS1 void*)g, (AS3 void*)l, 16, 0, 0);
}

// ---------- P1: row-normalize embeddings -> xn into a_cat, -xn into b_cat ----------
__global__ __launch_bounds__(256)
void prep_xn_kernel(const float* __restrict__ emb,
                    unsigned short* __restrict__ a_cat,
                    unsigned short* __restrict__ b_cat) {
  const int i = blockIdx.x;
  const int j = threadIdx.x;            // D == 256 == blockDim
  float x = emb[(size_t)i * D + j];
  float ss = x * x;
  #pragma unroll
  for (int o = 32; o > 0; o >>= 1) ss += __shfl_down(ss, o, 64);
  __shared__ float red[4];
  if ((threadIdx.x & 63) == 0) red[threadIdx.x >> 6] = ss;
  __syncthreads();
  float tot = red[0] + red[1] + red[2] + red[3];
  float inv = 1.0f / fmaxf(sqrtf(tot), 1e-8f);
  float xn = x * inv;
  a_cat[(size_t)i * KC + P + j] = f32_bf16(xn);
  b_cat[(size_t)i * KC + P + j] = f32_bf16(-xn);
}

// ---------- P2: cast Pred -> cat arrays + LDS-tiled transpose predT + weight loss ----------
__global__ __launch_bounds__(256)
void prep_pred_kernel(const float* __restrict__ pred,
                      const float* __restrict__ wts,
                      unsigned short* __restrict__ a_cat,
                      unsigned short* __restrict__ b_cat,
                      unsigned short* __restrict__ predT,
                      float* __restrict__ wtp) {
  __shared__ unsigned short t[P][72];   // 64 i-cols + pad
  const int tid = threadIdx.x;
  const int i0 = blockIdx.x * 64;
  float s = 0.f;
  #pragma unroll
  for (int k = 0; k < 32; ++k) {
    int e = k * 256 + tid;              // 0..8191 over 64x128 tile
    int ii = e >> 7, p = e & 127;
    size_t idx = (size_t)(i0 + ii) * P + p;
    float v = pred[idx];
    unsigned short h = f32_bf16(v);
    a_cat[(size_t)(i0 + ii) * KC + p] = h;
    b_cat[(size_t)(i0 + ii) * KC + p] = h;
    t[p][ii] = h;
    float d = v - wts[idx];
    s += d * d;
  }
  __syncthreads();
  #pragma unroll
  for (int k = 0; k < 32; ++k) {
    int e = k * 256 + tid;
    int p = e >> 6, ii = e & 63;
    predT[(size_t)p * N + i0 + ii] = t[p][ii];   // coalesced 128B runs
  }
  #pragma unroll
  for (int o = 32; o > 0; o >>= 1) s += __shfl_down(s, o, 64);
  __shared__ float red[4];
  if ((tid & 63) == 0) red[tid >> 6] = s;
  __syncthreads();
  if (tid == 0) wtp[blockIdx.x] = red[0] + red[1] + red[2] + red[3];
}

// ---------- coherence: 128x256 tiles, triangular grid, per-element sym weights ----------
__global__ __launch_bounds__(256, 2)
void coherence_kernel(const unsigned short* __restrict__ A,
                      const unsigned short* __restrict__ B,
                      float* __restrict__ cohp) {
  const int t = blockIdx.x;             // 0..1055; offset(bj) = bj^2 + bj
  int bj = (int)((sqrtf(4.0f * (float)t + 1.0f) - 1.0f) * 0.5f);
  while ((bj + 1) * (bj + 2) <= t) ++bj;      // (bj+1)^2+(bj+1) <= t
  while (bj * bj + bj > t) --bj;
  const int bi = t - bj * bj - bj;            // bi in [0, 2*bj+2)
  const int tid = threadIdx.x;
  __shared__ unsigned short As[128 * 32];     // 8 KB
  __shared__ unsigned short Bs[256 * 32];     // 16 KB
  const int w = tid >> 6, lane = tid & 63;
  const int wr = (w & 1) * 64, wc = (w >> 1) * 128;
  const int ml = lane & 15, kq = (lane >> 4) * 8;
  f32x4 acc[4][8] = {};
  const size_t abase = (size_t)bi * 128 * KC;
  const size_t bbase = (size_t)bj * 256 * KC;
  for (int k0 = 0; k0 < KC; k0 += 32) {
    __syncthreads();
    #pragma unroll
    for (int p = 0; p < 2; ++p) {           // A: 8 KB
      int e = p * 2048 + tid * 8;
      int row = e >> 5, col = e & 31;
      glds16(A + abase + (size_t)row * KC + k0 + col, &As[e]);
    }
    #pragma unroll
    for (int p = 0; p < 4; ++p) {           // B: 16 KB
      int e = p * 2048 + tid * 8;
      int row = e >> 5, col = e & 31;
      glds16(B + bbase + (size_t)row * KC + k0 + col, &Bs[e]);
    }
    __syncthreads();
    bf16x8 af[4], bf[8];
    #pragma unroll
    for (int a = 0; a < 4; ++a) af[a] = *(const bf16x8*)&As[(wr + a * 16 + ml) * 32 + kq];
    #pragma unroll
    for (int f = 0; f < 8; ++f) bf[f] = *(const bf16x8*)&Bs[(wc + f * 16 + ml) * 32 + kq];
    #pragma unroll
    for (int a = 0; a < 4; ++a)
      #pragma unroll
      for (int f = 0; f < 8; ++f)
        acc[a][f] = __builtin_amdgcn_mfma_f32_16x16x32_bf16(af[a], bf[f], acc[a][f], 0, 0, 0);
  }
  // C/D: col=lane&15 (B/j index), row=(lane>>4)*4+e (A/i index)  [m89/m91]
  float s = 0.f;
  const int ib = bi * 128 + wr + (lane >> 4) * 4;
  const int jb = bj * 256 + wc + ml;
  #pragma unroll
  for (int a = 0; a < 4; ++a)
    #pragma unroll
    for (int f = 0; f < 8; ++f)
      #pragma unroll
      for (int e = 0; e < 4; ++e) {
        int i = ib + a * 16 + e, j = jb + f * 16;
        float wgt = (i < j) ? 2.f : ((i == j) ? 1.f : 0.f);
        float c = acc[a][f][e];
        s += wgt * c * c;
      }
  #pragma unroll
  for (int o = 32; o > 0; o >>= 1) s += __shfl_down(s, o, 64);
  __shared__ float red[4];
  if (lane == 0) red[w] = s;
  __syncthreads();
  if (tid == 0) cohp[t] = red[0] + red[1] + red[2] + red[3];
}

// ---------- structure v4: ONE barrier, 32 rows/wave, B fully staged for K-range 512 ----------
// grid (64 row-blocks, 16 k-slices); block = 4 waves x 32 rows = 128 rows.
// LDS: Bs[16 chunks][128 p][32 k] bf16 = 128 KB -> 1 block/CU, 4 waves.
__global__ __launch_bounds__(256, 1)
void structure_mfma_kernel(const float* __restrict__ adj,
                           const unsigned short* __restrict__ predT,
                           float* __restrict__ cpart) {
  __shared__ unsigned short Bs[16 * 128 * 32];
  const int tid = threadIdx.x;
  const int w = tid >> 6, lane = tid & 63;
  const int ml = lane & 15, kq = (lane >> 4) * 8;
  const int row0 = blockIdx.x * 128 + w * 32;
  const int kbeg = blockIdx.y * 512;

  // stage ALL of B once: 8192 16-B groups; lane-linear LDS dest (glds16 requirement)
  #pragma unroll 4
  for (int it = 0; it < 32; ++it) {
    int base16 = it * 256 + w * 64;           // wave-uniform
    int L16 = base16 + lane;
    int c = L16 >> 9, p = (L16 >> 2) & 127, g = L16 & 3;
    glds16(predT + (size_t)p * N + kbeg + c * 32 + g * 8,
           (char*)Bs + (size_t)base16 * 16);
  }
  __syncthreads();                             // the ONLY barrier

  const float* a0p = adj + (size_t)(row0 + ml) * N + kbeg + kq;
  const float* a1p = a0p + (size_t)16 * N;
  f32x4 acc[2][8] = {};
  float4 ring[3][2][2];                        // [slot][rowgroup][half]
  #pragma unroll
  for (int s = 0; s < 3; ++s) {
    ring[s][0][0] = *(const float4*)(a0p + s * 32);
    ring[s][0][1] = *(const float4*)(a0p + s * 32 + 4);
    ring[s][1][0] = *(const float4*)(a1p + s * 32);
    ring[s][1][1] = *(const float4*)(a1p + s * 32 + 4);
  }
  #pragma unroll
  for (int c = 0; c < 16; ++c) {
    float4 v00 = ring[c % 3][0][0], v01 = ring[c % 3][0][1];
    float4 v10 = ring[c % 3][1][0], v11 = ring[c % 3][1][1];
    if (c < 13) {
      ring[c % 3][0][0] = *(const float4*)(a0p + (c + 3) * 32);
      ring[c % 3][0][1] = *(const float4*)(a0p + (c + 3) * 32 + 4);
      ring[c % 3][1][0] = *(const float4*)(a1p + (c + 3) * 32);
      ring[c % 3][1][1] = *(const float4*)(a1p + (c + 3) * 32 + 4);
    }
    union { bf16x8 v; unsigned short s[8]; } ah0, ah1;
    ah0.s[0] = f32_bf16(v00.x); ah0.s[1] = f32_bf16(v00.y);
    ah0.s[2] = f32_bf16(v00.z); ah0.s[3] = f32_bf16(v00.w);
    ah0.s[4] = f32_bf16(v01.x); ah0.s[5] = f32_bf16(v01.y);
    ah0.s[6] = f32_bf16(v01.z); ah0.s[7] = f32_bf16(v01.w);
    ah1.s[0] = f32_bf16(v10.x); ah1.s[1] = f32_bf16(v10.y);
    ah1.s[2] = f32_bf16(v10.z); ah1.s[3] = f32_bf16(v10.w);
    ah1.s[4] = f32_bf16(v11.x); ah1.s[5] = f32_bf16(v11.y);
    ah1.s[6] = f32_bf16(v11.z); ah1.s[7] = f32_bf16(v11.w);
    #pragma unroll
    for (int f = 0; f < 8; ++f) {
      bf16x8 bf = *(const bf16x8*)&Bs[(c * 128 + f * 16 + ml) * 32 + kq];
      acc[0][f] = __builtin_amdgcn_mfma_f32_16x16x32_bf16(ah0.v, bf, acc[0][f], 0, 0, 0);
      acc[1][f] = __builtin_amdgcn_mfma_f32_16x16x32_bf16(ah1.v, bf, acc[1][f], 0, 0, 0);
    }
  }
  // epilogue: fp32 partial slice; full 64-B granule runs
  float* cp = cpart + (size_t)blockIdx.y * ((size_t)N * P);
  #pragma unroll
  for (int rg = 0; rg < 2; ++rg) {
    const int rb = row0 + rg * 16 + (lane >> 4) * 4;
    #pragma unroll
    for (int f = 0; f < 8; ++f)
      #pragma unroll
      for (int e = 0; e < 4; ++e)
        cp[(size_t)(rb + e) * P + f * 16 + ml] = acc[rg][f][e];
  }
}

// ---------- structure reduce: sum 16 fp32 partial slices, (pred - C)^2 ----------
__global__ __launch_bounds__(256)
void structure_reduce_kernel(const float* __restrict__ cpart,
                             const float* __restrict__ pred,
                             float* __restrict__ strp) {
  const int tid = threadIdx.x;
  const size_t base = ((size_t)blockIdx.x * 256 + tid) * 8;
  const float4 p0 = *(const float4*)(pred + base);
  const float4 p1 = *(const float4*)(pred + base + 4);
  float c[8] = {};
  #pragma unroll
  for (int sl = 0; sl < 16; ++sl) {
    float4 c0 = *(const float4*)(cpart + (size_t)sl * ((size_t)N * P) + base);
    float4 c1 = *(const float4*)(cpart + (size_t)sl * ((size_t)N * P) + base + 4);
    c[0] += c0.x; c[1] += c0.y; c[2] += c0.z; c[3] += c0.w;
    c[4] += c1.x; c[5] += c1.y; c[6] += c1.z; c[7] += c1.w;
  }
  const float pv[8] = {p0.x, p0.y, p0.z, p0.w, p1.x, p1.y, p1.z, p1.w};
  float s = 0.f;
  #pragma unroll
  for (int e = 0; e < 8; ++e) { float d = pv[e] - c[e]; s += d * d; }
  #pragma unroll
  for (int o = 32; o > 0; o >>= 1) s += __shfl_down(s, o, 64);
  __shared__ float red[4];
  if ((tid & 63) == 0) red[tid >> 6] = s;
  __syncthreads();
  if (tid == 0) strp[blockIdx.x] = red[0] + red[1] + red[2] + red[3];
}

// ---------- final: fp64 reduce of partials, combine losses ----------
__global__ __launch_bounds__(256)
void finalize_kernel(const float* __restrict__ cohp,
                     const float* __restrict__ wtp,
                     const float* __restrict__ strp,
                     float* __restrict__ out) {
  const int tid = threadIdx.x;
  double sc = 0, sw = 0, ss = 0;
  for (int i = tid; i < 1056; i += 256) sc += (double)cohp[i];
  for (int i = tid; i < 128;  i += 256) sw += (double)wtp[i];
  for (int i = tid; i < 512;  i += 256) ss += (double)strp[i];
  #pragma unroll
  for (int o = 32; o > 0; o >>= 1) {
    sc += __shfl_down(sc, o, 64);
    sw += __shfl_down(sw, o, 64);
    ss += __shfl_down(ss, o, 64);
  }
  __shared__ double rd[3][4];
  const int w = tid >> 6, lane = tid & 63;
  if (lane == 0) { rd[0][w] = sc; rd[1][w] = sw; rd[2][w] = ss; }
  __syncthreads();
  if (tid == 0) {
    double c  = rd[0][0] + rd[0][1] + rd[0][2] + rd[0][3];
    double wv = rd[1][0] + rd[1][1] + rd[1][2] + rd[1][3];
    double st = rd[2][0] + rd[2][1] + rd[2][2] + rd[2][3];
    out[0] = (float)(c / ((double)N * (double)N) +
                     st / ((double)N * (double)P) +
                     wv / ((double)N * (double)P));
  }
}

extern "C" void kernel_launch(void* const* d_in, const int* in_sizes, int n_in,
                              void* d_out, int out_size, void* d_ws, size_t ws_size,
                              hipStream_t stream) {
  const float* pred = (const float*)d_in[0];   // [8192,128]
  const float* emb  = (const float*)d_in[1];   // [8192,256]
  const float* adj  = (const float*)d_in[2];   // [8192,8192]
  const float* wts  = (const float*)d_in[3];   // [8192,128]
  float* out = (float*)d_out;
  char* ws = (char*)d_ws;
  // ws layout (ws_size >= 1 GB per fill counter): no overlays needed.
  unsigned short* a_cat = (unsigned short*)ws;               // [8192,384] bf16, 6 MB
  unsigned short* b_cat = (unsigned short*)(ws + 6291456);   // [8192,384] bf16, 6 MB
  unsigned short* predT = (unsigned short*)(ws + 12582912);  // [128,8192] bf16, 2 MB
  float*          cpart = (float*)(ws + 16777216);           // 16 x [8192,128] fp32 = 64 MB
  float* cohp = (float*)(ws + 83886080);                     // 1056
  float* wtp  = cohp + 1056;                                 // 128
  float* strp = wtp + 128;                                   // 512

  prep_xn_kernel  <<<N,          256, 0, stream>>>(emb, a_cat, b_cat);
  prep_pred_kernel<<<N / 64,     256, 0, stream>>>(pred, wts, a_cat, b_cat, predT, wtp);
  coherence_kernel<<<1056,       256, 0, stream>>>(a_cat, b_cat, cohp);
  structure_mfma_kernel<<<dim3(64, 16), 256, 0, stream>>>(adj, predT, cpart);
  structure_reduce_kernel<<<512, 256, 0, stream>>>(cpart, pred, strp);
  finalize_kernel <<<1,          256, 0, stream>>>(cohp, wtp, strp, out);
}

// Round 5
// 495.540 us; speedup vs baseline: 1.0329x; 1.0329x over previous
//
#include <hip/hip_runtime.h>
#include <hip/hip_bf16.h>

#define AS1 __attribute__((address_space(1)))
#define AS3 __attribute__((address_space(3)))

typedef __attribute__((ext_vector_type(8))) __bf16 bf16x8;
typedef __attribute__((ext_vector_type(8))) unsigned short ushort8;
typedef __attribute__((ext_vector_type(4))) float f32x4;

static constexpr int N  = 8192;
static constexpr int P  = 128;
static constexpr int D  = 256;
static constexpr int KC = 384;   // P + D concatenated K

__device__ __forceinline__ unsigned short f32_bf16(float f) {
  union { float f; unsigned u; } v; v.f = f;
  unsigned r = v.u + 0x7fffu + ((v.u >> 16) & 1u);   // round-to-nearest-even
  return (unsigned short)(r >> 16);
}

__device__ __forceinline__ void glds16(const void* g, void* l) {
  __builtin_amdgcn_global_load_lds((const AS1 void*)g, (AS3 void*)l, 16, 0, 0);
}

// pack 4 floats -> 4 bf16 (RNE) using HW packed cvt where available
__device__ __forceinline__ void pack4(unsigned short* d, float a, float b, float c, float e) {
  __hip_bfloat162 h0 = __float22bfloat162_rn({a, b});
  __hip_bfloat162 h1 = __float22bfloat162_rn({c, e});
  *(__hip_bfloat162*)(d)     = h0;
  *(__hip_bfloat162*)(d + 2) = h1;
}

// ---------- P1: row-normalize embeddings -> xn into a_cat, -xn into b_cat ----------
__global__ __launch_bounds__(256)
void prep_xn_kernel(const float* __restrict__ emb,
                    unsigned short* __restrict__ a_cat,
                    unsigned short* __restrict__ b_cat) {
  const int i = blockIdx.x;
  const int j = threadIdx.x;            // D == 256 == blockDim
  float x = emb[(size_t)i * D + j];
  float ss = x * x;
  #pragma unroll
  for (int o = 32; o > 0; o >>= 1) ss += __shfl_down(ss, o, 64);
  __shared__ float red[4];
  if ((threadIdx.x & 63) == 0) red[threadIdx.x >> 6] = ss;
  __syncthreads();
  float tot = red[0] + red[1] + red[2] + red[3];
  float inv = 1.0f / fmaxf(sqrtf(tot), 1e-8f);
  float xn = x * inv;
  a_cat[(size_t)i * KC + P + j] = f32_bf16(xn);
  b_cat[(size_t)i * KC + P + j] = f32_bf16(-xn);
}

// ---------- P2: cast Pred -> cat arrays + LDS-tiled transpose predT + weight loss ----------
__global__ __launch_bounds__(256)
void prep_pred_kernel(const float* __restrict__ pred,
                      const float* __restrict__ wts,
                      unsigned short* __restrict__ a_cat,
                      unsigned short* __restrict__ b_cat,
                      unsigned short* __restrict__ predT,
                      float* __restrict__ wtp) {
  __shared__ unsigned short t[P][72];   // 64 i-cols + pad
  const int tid = threadIdx.x;
  const int i0 = blockIdx.x * 64;
  float s = 0.f;
  #pragma unroll
  for (int k = 0; k < 32; ++k) {
    int e = k * 256 + tid;              // 0..8191 over 64x128 tile
    int ii = e >> 7, p = e & 127;
    size_t idx = (size_t)(i0 + ii) * P + p;
    float v = pred[idx];
    unsigned short h = f32_bf16(v);
    a_cat[(size_t)(i0 + ii) * KC + p] = h;
    b_cat[(size_t)(i0 + ii) * KC + p] = h;
    t[p][ii] = h;
    float d = v - wts[idx];
    s += d * d;
  }
  __syncthreads();
  #pragma unroll
  for (int k = 0; k < 32; ++k) {
    int e = k * 256 + tid;
    int p = e >> 6, ii = e & 63;
    predT[(size_t)p * N + i0 + ii] = t[p][ii];   // coalesced 128B runs
  }
  #pragma unroll
  for (int o = 32; o > 0; o >>= 1) s += __shfl_down(s, o, 64);
  __shared__ float red[4];
  if ((tid & 63) == 0) red[tid >> 6] = s;
  __syncthreads();
  if (tid == 0) wtp[blockIdx.x] = red[0] + red[1] + red[2] + red[3];
}

// ---------- coherence: 128x256 tiles, triangular grid, per-element sym weights ----------
__global__ __launch_bounds__(256, 2)
void coherence_kernel(const unsigned short* __restrict__ A,
                      const unsigned short* __restrict__ B,
                      float* __restrict__ cohp) {
  const int t = blockIdx.x;             // 0..1055; offset(bj) = bj^2 + bj
  int bj = (int)((sqrtf(4.0f * (float)t + 1.0f) - 1.0f) * 0.5f);
  while ((bj + 1) * (bj + 2) <= t) ++bj;      // (bj+1)^2+(bj+1) <= t
  while (bj * bj + bj > t) --bj;
  const int bi = t - bj * bj - bj;            // bi in [0, 2*bj+2)
  const int tid = threadIdx.x;
  __shared__ unsigned short As[128 * 32];     // 8 KB
  __shared__ unsigned short Bs[256 * 32];     // 16 KB
  const int w = tid >> 6, lane = tid & 63;
  const int wr = (w & 1) * 64, wc = (w >> 1) * 128;
  const int ml = lane & 15, kq = (lane >> 4) * 8;
  f32x4 acc[4][8] = {};
  const size_t abase = (size_t)bi * 128 * KC;
  const size_t bbase = (size_t)bj * 256 * KC;
  for (int k0 = 0; k0 < KC; k0 += 32) {
    __syncthreads();
    #pragma unroll
    for (int p = 0; p < 2; ++p) {           // A: 8 KB
      int e = p * 2048 + tid * 8;
      int row = e >> 5, col = e & 31;
      glds16(A + abase + (size_t)row * KC + k0 + col, &As[e]);
    }
    #pragma unroll
    for (int p = 0; p < 4; ++p) {           // B: 16 KB
      int e = p * 2048 + tid * 8;
      int row = e >> 5, col = e & 31;
      glds16(B + bbase + (size_t)row * KC + k0 + col, &Bs[e]);
    }
    __syncthreads();
    bf16x8 af[4], bf[8];
    #pragma unroll
    for (int a = 0; a < 4; ++a) af[a] = *(const bf16x8*)&As[(wr + a * 16 + ml) * 32 + kq];
    #pragma unroll
    for (int f = 0; f < 8; ++f) bf[f] = *(const bf16x8*)&Bs[(wc + f * 16 + ml) * 32 + kq];
    #pragma unroll
    for (int a = 0; a < 4; ++a)
      #pragma unroll
      for (int f = 0; f < 8; ++f)
        acc[a][f] = __builtin_amdgcn_mfma_f32_16x16x32_bf16(af[a], bf[f], acc[a][f], 0, 0, 0);
  }
  // C/D: col=lane&15 (B/j index), row=(lane>>4)*4+e (A/i index)  [m89/m91]
  float s = 0.f;
  const int ib = bi * 128 + wr + (lane >> 4) * 4;
  const int jb = bj * 256 + wc + ml;
  #pragma unroll
  for (int a = 0; a < 4; ++a)
    #pragma unroll
    for (int f = 0; f < 8; ++f)
      #pragma unroll
      for (int e = 0; e < 4; ++e) {
        int i = ib + a * 16 + e, j = jb + f * 16;
        float wgt = (i < j) ? 2.f : ((i == j) ? 1.f : 0.f);
        float c = acc[a][f][e];
        s += wgt * c * c;
      }
  #pragma unroll
  for (int o = 32; o > 0; o >>= 1) s += __shfl_down(s, o, 64);
  __shared__ float red[4];
  if (lane == 0) red[w] = s;
  __syncthreads();
  if (tid == 0) cohp[t] = red[0] + red[1] + red[2] + red[3];
}

// ---------- structure v5: exact-fit grid (2 blocks/CU, 1 generation), B dbuf in LDS,
// continuous adj register ring across rounds, 1 barrier/round ----------
// grid (64 row-blocks, 8 k-slices); block = 4 waves x 32 rows = 128 rows, K-slice 1024.
// LDS: Bs[2][4 chunks][128 p][32 k] bf16 = 2 x 32 KB = 64 KB -> 2 blocks/CU.
__global__ __launch_bounds__(256, 2)
void structure_mfma_kernel(const float* __restrict__ adj,
                           const unsigned short* __restrict__ predT,
                           float* __restrict__ cpart) {
  __shared__ unsigned short Bs[2][4 * 128 * 32];
  const int tid = threadIdx.x;
  const int w = tid >> 6, lane = tid & 63;
  const int ml = lane & 15, kq = (lane >> 4) * 8;
  const int row0 = blockIdx.x * 128 + w * 32;
  const int kbeg = blockIdx.y * 1024;

  // stage round r (k = kbeg + r*128 .. +128) into Bs[buf]: 2048 16-B groups [c:4][p:128][g:4]
  #define STAGE(r, buf)                                                          \
    _Pragma("unroll")                                                            \
    for (int it = 0; it < 8; ++it) {                                             \
      int base16 = it * 256 + w * 64;                                            \
      int L16 = base16 + lane;                                                   \
      int c = L16 >> 9, p = (L16 >> 2) & 127, g = L16 & 3;                       \
      glds16(predT + (size_t)p * N + kbeg + (r) * 128 + c * 32 + g * 8,          \
             (char*)Bs[buf] + (size_t)base16 * 16);                              \
    }

  STAGE(0, 0)                                   // oldest in vmcnt FIFO

  const float* a0p = adj + (size_t)(row0 + ml) * N + kbeg + kq;
  const float* a1p = a0p + (size_t)16 * N;
  f32x4 acc[2][8] = {};
  float4 ring[3][2][2];                         // [slot][rowgroup][half]
  #pragma unroll
  for (int s = 0; s < 3; ++s) {
    ring[s][0][0] = *(const float4*)(a0p + s * 32);
    ring[s][0][1] = *(const float4*)(a0p + s * 32 + 4);
    ring[s][1][0] = *(const float4*)(a1p + s * 32);
    ring[s][1][1] = *(const float4*)(a1p + s * 32 + 4);
  }
  __syncthreads();                              // Bs[0] ready (drain completes ring too)

  #pragma unroll
  for (int r = 0; r < 8; ++r) {
    if (r < 7) { STAGE(r + 1, (r + 1) & 1) }    // hide staging behind this round's compute
    #pragma unroll
    for (int cc = 0; cc < 4; ++cc) {
      const int g = r * 4 + cc;                 // global chunk 0..31 (compile-time)
      float4 v00 = ring[g % 3][0][0], v01 = ring[g % 3][0][1];
      float4 v10 = ring[g % 3][1][0], v11 = ring[g % 3][1][1];
      if (g < 29) {                             // ring never restarts across rounds
        ring[g % 3][0][0] = *(const float4*)(a0p + (g + 3) * 32);
        ring[g % 3][0][1] = *(const float4*)(a0p + (g + 3) * 32 + 4);
        ring[g % 3][1][0] = *(const float4*)(a1p + (g + 3) * 32);
        ring[g % 3][1][1] = *(const float4*)(a1p + (g + 3) * 32 + 4);
      }
      union { bf16x8 v; unsigned short s[8]; } ah0, ah1;
      pack4(&ah0.s[0], v00.x, v00.y, v00.z, v00.w);
      pack4(&ah0.s[4], v01.x, v01.y, v01.z, v01.w);
      pack4(&ah1.s[0], v10.x, v10.y, v10.z, v10.w);
      pack4(&ah1.s[4], v11.x, v11.y, v11.z, v11.w);
      #pragma unroll
      for (int f = 0; f < 8; ++f) {
        bf16x8 bf = *(const bf16x8*)&Bs[r & 1][(cc * 128 + f * 16 + ml) * 32 + kq];
        acc[0][f] = __builtin_amdgcn_mfma_f32_16x16x32_bf16(ah0.v, bf, acc[0][f], 0, 0, 0);
        acc[1][f] = __builtin_amdgcn_mfma_f32_16x16x32_bf16(ah1.v, bf, acc[1][f], 0, 0, 0);
      }
    }
    __syncthreads();                            // Bs[(r+1)&1] staged & Bs[r&1] free
  }
  #undef STAGE

  // epilogue: fp32 partial slice; full 64-B granule runs
  float* cp = cpart + (size_t)blockIdx.y * ((size_t)N * P);
  #pragma unroll
  for (int rg = 0; rg < 2; ++rg) {
    const int rb = row0 + rg * 16 + (lane >> 4) * 4;
    #pragma unroll
    for (int f = 0; f < 8; ++f)
      #pragma unroll
      for (int e = 0; e < 4; ++e)
        cp[(size_t)(rb + e) * P + f * 16 + ml] = acc[rg][f][e];
  }
}

// ---------- structure reduce: sum 8 fp32 partial slices, (pred - C)^2 ----------
__global__ __launch_bounds__(256)
void structure_reduce_kernel(const float* __restrict__ cpart,
                             const float* __restrict__ pred,
                             float* __restrict__ strp) {
  const int tid = threadIdx.x;
  const size_t base = ((size_t)blockIdx.x * 256 + tid) * 8;
  const float4 p0 = *(const float4*)(pred + base);
  const float4 p1 = *(const float4*)(pred + base + 4);
  float c[8] = {};
  #pragma unroll
  for (int sl = 0; sl < 8; ++sl) {
    float4 c0 = *(const float4*)(cpart + (size_t)sl * ((size_t)N * P) + base);
    float4 c1 = *(const float4*)(cpart + (size_t)sl * ((size_t)N * P) + base + 4);
    c[0] += c0.x; c[1] += c0.y; c[2] += c0.z; c[3] += c0.w;
    c[4] += c1.x; c[5] += c1.y; c[6] += c1.z; c[7] += c1.w;
  }
  const float pv[8] = {p0.x, p0.y, p0.z, p0.w, p1.x, p1.y, p1.z, p1.w};
  float s = 0.f;
  #pragma unroll
  for (int e = 0; e < 8; ++e) { float d = pv[e] - c[e]; s += d * d; }
  #pragma unroll
  for (int o = 32; o > 0; o >>= 1) s += __shfl_down(s, o, 64);
  __shared__ float red[4];
  if ((tid & 63) == 0) red[tid >> 6] = s;
  __syncthreads();
  if (tid == 0) strp[blockIdx.x] = red[0] + red[1] + red[2] + red[3];
}

// ---------- final: fp64 reduce of partials, combine losses ----------
__global__ __launch_bounds__(256)
void finalize_kernel(const float* __restrict__ cohp,
                     const float* __restrict__ wtp,
                     const float* __restrict__ strp,
                     float* __restrict__ out) {
  const int tid = threadIdx.x;
  double sc = 0, sw = 0, ss = 0;
  for (int i = tid; i < 1056; i += 256) sc += (double)cohp[i];
  for (int i = tid; i < 128;  i += 256) sw += (double)wtp[i];
  for (int i = tid; i < 512;  i += 256) ss += (double)strp[i];
  #pragma unroll
  for (int o = 32; o > 0; o >>= 1) {
    sc += __shfl_down(sc, o, 64);
    sw += __shfl_down(sw, o, 64);
    ss += __shfl_down(ss, o, 64);
  }
  __shared__ double rd[3][4];
  const int w = tid >> 6, lane = tid & 63;
  if (lane == 0) { rd[0][w] = sc; rd[1][w] = sw; rd[2][w] = ss; }
  __syncthreads();
  if (tid == 0) {
    double c  = rd[0][0] + rd[0][1] + rd[0][2] + rd[0][3];
    double wv = rd[1][0] + rd[1][1] + rd[1][2] + rd[1][3];
    double st = rd[2][0] + rd[2][1] + rd[2][2] + rd[2][3];
    out[0] = (float)(c / ((double)N * (double)N) +
                     st / ((double)N * (double)P) +
                     wv / ((double)N * (double)P));
  }
}

extern "C" void kernel_launch(void* const* d_in, const int* in_sizes, int n_in,
                              void* d_out, int out_size, void* d_ws, size_t ws_size,
                              hipStream_t stream) {
  const float* pred = (const float*)d_in[0];   // [8192,128]
  const float* emb  = (const float*)d_in[1];   // [8192,256]
  const float* adj  = (const float*)d_in[2];   // [8192,8192]
  const float* wts  = (const float*)d_in[3];   // [8192,128]
  float* out = (float*)d_out;
  char* ws = (char*)d_ws;
  unsigned short* a_cat = (unsigned short*)ws;               // [8192,384] bf16, 6 MB
  unsigned short* b_cat = (unsigned short*)(ws + 6291456);   // [8192,384] bf16, 6 MB
  unsigned short* predT = (unsigned short*)(ws + 12582912);  // [128,8192] bf16, 2 MB
  float*          cpart = (float*)(ws + 16777216);           // 8 x [8192,128] fp32 = 32 MB
  float* cohp = (float*)(ws + 83886080);                     // 1056
  float* wtp  = cohp + 1056;                                 // 128
  float* strp = wtp + 128;                                   // 512

  prep_xn_kernel  <<<N,          256, 0, stream>>>(emb, a_cat, b_cat);
  prep_pred_kernel<<<N / 64,     256, 0, stream>>>(pred, wts, a_cat, b_cat, predT, wtp);
  coherence_kernel<<<1056,       256, 0, stream>>>(a_cat, b_cat, cohp);
  structure_mfma_kernel<<<dim3(64, 8), 256, 0, stream>>>(adj, predT, cpart);
  structure_reduce_kernel<<<512, 256, 0, stream>>>(cpart, pred, strp);
  finalize_kernel <<<1,          256, 0, stream>>>(cohp, wtp, strp, out);
}